// Round 10
// baseline (798.658 us; speedup 1.0000x reference)
//
#include <hip/hip_runtime.h>

#define HIDDEN 51
#define LSEQ 1000
#define UNROLL 8    // steps per group; LSEQ % UNROLL == 0

typedef float v2f __attribute__((ext_vector_type(2)));

// Branch-free tanh: tanh(v) = 1 - 2/(exp2(2*log2e*v)+1). Saturates to +/-1.
__device__ __forceinline__ float fast_tanh(float v) {
    float e = __builtin_amdgcn_exp2f(v * 2.885390081777927f);  // 2*log2(e)
    float r = __builtin_amdgcn_rcpf(e + 1.0f);
    return fmaf(-2.0f, r, 1.0f);
}

// One wave per batch element (1024 waves = 1/SIMD), no block barriers.
// Evidence-driven composition of R8+R9:
//  - v2f Up[4][26] + v_pk_fma_f32: empirically avoids the AGPR-copy tax that
//    the scalar float U[4][52] layout pays (R9: +330 busy cyc/step). pk is
//    half-rate on fp32 (same VALU-busy as scalar) but halves issue slots.
//  - ALL 13 float4 h-broadcast loads hoisted ahead of the FMA block (R9:
//    stall 722->562): one exposed LDS round-trip/step, rest drains under
//    the ~416-cycle FMA issue stream.
//  - x double-buffered across groups: next group's 8 uniform loads issue at
//    group top, consumed next group -> L2 latency fully hidden.
//  - Output butterflies pipelined one group behind, ONE PER STEP, placed
//    right after the h-write: the 6-deep swizzle chain executes in the
//    LDS write->read shadow (dead time at 1 wave/SIMD). Stores are 2x
//    float4 per group for the previous group; drained after the loop.
__global__ __launch_bounds__(64, 1) void lstm_seq_kernel(
    const float* __restrict__ x,
    const float* __restrict__ W_w,
    const float* __restrict__ W_b,
    const float* __restrict__ U_w,
    const float* __restrict__ U_b,
    const float* __restrict__ lin_w,
    const float* __restrict__ lin_b,
    float* __restrict__ out)
{
    __shared__ __attribute__((aligned(16))) float hb[64];  // h broadcast

    const int b    = blockIdx.x;
    const int lane = threadIdx.x;        // 0..63
    const bool active = lane < HIDDEN;   // lanes 51..63 produce exact zeros
    const int m = active ? lane : 0;

    float ww[4], bb[4];
#pragma unroll
    for (int g = 0; g < 4; ++g) {
        const int row = m + g * HIDDEN;
        ww[g] = active ? W_w[row] : 0.f;
        bb[g] = active ? (W_b[row] + U_b[row]) : 0.f;
    }
    const float lw = active ? lin_w[m] : 0.f;
    const float lb = lin_b[0];

    // U packed over k-pairs: Up[g][j] = {U[row][2j], U[row][2j+1]}, j<26.
    // k==51 zero pad (matches hb[51]==0 from lane 51's h==0).
    v2f Up[4][26];
#pragma unroll
    for (int j = 0; j < 26; ++j) {
        const int k0 = 2 * j, k1 = 2 * j + 1;
#pragma unroll
        for (int g = 0; g < 4; ++g) {
            const int row = m + g * HIDDEN;
            v2f u;
            u.x = (active && k0 < HIDDEN) ? U_w[row * HIDDEN + k0] : 0.f;
            u.y = (active && k1 < HIDDEN) ? U_w[row * HIDDEN + k1] : 0.f;
            Up[g][j] = u;
        }
    }

    float h = 0.f, c = 0.f;
    const float* __restrict__ xrow = x + (long)b * LSEQ;
    float* __restrict__ orow = out + (long)b * LSEQ;

    hb[lane] = 0.f;                       // single wave: in-order LDS pipe
    __builtin_amdgcn_wave_barrier();      // ordering insurance (no-op inst)

    float xg[UNROLL], rbp[UNROLL];        // current-group x; prev-group h*lw
#pragma unroll
    for (int s = 0; s < UNROLL; ++s) xg[s] = xrow[s];  // prime group 0

    for (int T = 0; T < LSEQ; T += UNROLL) {
        // Prefetch NEXT group's x (uniform loads; consumed next iteration).
        const int Tn = (T + UNROLL < LSEQ) ? (T + UNROLL) : T;
        float xn[UNROLL];
#pragma unroll
        for (int s = 0; s < UNROLL; ++s) xn[s] = xrow[Tn + s];

        float rbc[UNROLL];
#pragma unroll
        for (int s = 0; s < UNROLL; ++s) {
            // ---- hoisted h broadcast: 13 x ds_read_b128 (same-address ----
            // ---- broadcast, conflict-free) into VGPRs.               ----
            float4 hv[13];
#pragma unroll
            for (int q = 0; q < 13; ++q)
                hv[q] = *(const float4*)&hb[q * 4];

            // ---- packed FMA block (identical arithmetic to R8). ----
            v2f a0 = {0.f, 0.f}, a1 = {0.f, 0.f};
            v2f a2 = {0.f, 0.f}, a3 = {0.f, 0.f};
#pragma unroll
            for (int q = 0; q < 13; ++q) {
                const v2f hlo = {hv[q].x, hv[q].y};
                const v2f hhi = {hv[q].z, hv[q].w};
                a0 = __builtin_elementwise_fma(hlo, Up[0][2 * q], a0);
                a1 = __builtin_elementwise_fma(hlo, Up[1][2 * q], a1);
                a2 = __builtin_elementwise_fma(hlo, Up[2][2 * q], a2);
                a3 = __builtin_elementwise_fma(hlo, Up[3][2 * q], a3);
                a0 = __builtin_elementwise_fma(hhi, Up[0][2 * q + 1], a0);
                a1 = __builtin_elementwise_fma(hhi, Up[1][2 * q + 1], a1);
                a2 = __builtin_elementwise_fma(hhi, Up[2][2 * q + 1], a2);
                a3 = __builtin_elementwise_fma(hhi, Up[3][2 * q + 1], a3);
            }
            const float gi = a0.x + a0.y + fmaf(xg[s], ww[0], bb[0]);
            const float gf = a1.x + a1.y + fmaf(xg[s], ww[1], bb[1]);
            const float gg = a2.x + a2.y + fmaf(xg[s], ww[2], bb[2]);
            const float go = a3.x + a3.y + fmaf(xg[s], ww[3], bb[3]);

            // NOTE: faithful to reference -- no sigmoid on gates.
            c = fmaf(gf, c, gi * gg);
            h = go * fast_tanh(c);        // inactive lanes stay exactly 0
            rbc[s] = h * lw;

            __builtin_amdgcn_wave_barrier();  // reads above precede write
            hb[lane] = h;
            __builtin_amdgcn_wave_barrier();  // write precedes next reads

            // Pipelined butterfly for the PREVIOUS group's step s, executed
            // in the LDS write->read shadow. Register-only inputs.
#pragma unroll
            for (int off = 32; off > 0; off >>= 1)
                rbp[s] += __shfl_xor(rbp[s], off, 64);
        }

        // Store previous group's outputs (reduced in rbp) as 2 x float4.
        if (T > 0 && lane == 0) {
            float4 o0 = {rbp[0] + lb, rbp[1] + lb, rbp[2] + lb, rbp[3] + lb};
            float4 o1 = {rbp[4] + lb, rbp[5] + lb, rbp[6] + lb, rbp[7] + lb};
            *(float4*)&orow[T - UNROLL]     = o0;  // 16B-aligned (T mult of 8)
            *(float4*)&orow[T - UNROLL + 4] = o1;
        }

#pragma unroll
        for (int s = 0; s < UNROLL; ++s) { rbp[s] = rbc[s]; xg[s] = xn[s]; }
    }

    // Drain: butterfly + store for the last group.
#pragma unroll
    for (int s = 0; s < UNROLL; ++s) {
#pragma unroll
        for (int off = 32; off > 0; off >>= 1)
            rbp[s] += __shfl_xor(rbp[s], off, 64);
    }
    if (lane == 0) {
        float4 o0 = {rbp[0] + lb, rbp[1] + lb, rbp[2] + lb, rbp[3] + lb};
        float4 o1 = {rbp[4] + lb, rbp[5] + lb, rbp[6] + lb, rbp[7] + lb};
        *(float4*)&orow[LSEQ - UNROLL]     = o0;
        *(float4*)&orow[LSEQ - UNROLL + 4] = o1;
    }
}

extern "C" void kernel_launch(void* const* d_in, const int* in_sizes, int n_in,
                              void* d_out, int out_size, void* d_ws, size_t ws_size,
                              hipStream_t stream) {
    const float* x     = (const float*)d_in[0];
    const float* W_w   = (const float*)d_in[1];
    const float* W_b   = (const float*)d_in[2];
    const float* U_w   = (const float*)d_in[3];
    const float* U_b   = (const float*)d_in[4];
    const float* lin_w = (const float*)d_in[5];
    const float* lin_b = (const float*)d_in[6];
    // d_in[7] = future (static 0; out_size == B*LSEQ)
    float* out = (float*)d_out;

    const int B = in_sizes[0] / LSEQ;  // 1024
    lstm_seq_kernel<<<dim3(B), dim3(64), 0, stream>>>(
        x, W_w, W_b, U_w, U_b, lin_w, lin_b, out);
}